// Round 4
// baseline (328.181 us; speedup 1.0000x reference)
//
#include <hip/hip_runtime.h>

#define NTOK 8192
#define DDIM 1024
#define HDIM 2048
#define ODIM 1024
#define NEXP 8
#define OUTW (ODIM + NEXP)   // 1032
#define MT_MAX 64            // worst-case m-tiles per expert

typedef __bf16 bf16_t;
typedef bf16_t bf16x8 __attribute__((ext_vector_type(8)));
typedef bf16_t bf16x4 __attribute__((ext_vector_type(4)));
typedef float f32x4 __attribute__((ext_vector_type(4)));

__device__ __forceinline__ void gld_lds16(bf16_t* lds, const bf16_t* g) {
  __builtin_amdgcn_global_load_lds(
      (__attribute__((address_space(1))) void*)g,
      (__attribute__((address_space(3))) void*)lds, 16, 0, 0);
}

__global__ void zero_cnt_kernel(int* cnt) {
  if (threadIdx.x < NEXP) cnt[threadIdx.x] = 0;
}

// Per-block LDS histogram: 256 global atomics total instead of 8192.
__global__ void route_kernel(const int* __restrict__ idx, float* __restrict__ out,
                             int* __restrict__ rank, int* cnt) {
  __shared__ int lcnt[NEXP];
  __shared__ int lbase[NEXP];
  int t = threadIdx.x;
  if (t < NEXP) lcnt[t] = 0;
  __syncthreads();
  int n = blockIdx.x * 256 + t;
  int e = idx[n];
  int lr = atomicAdd(&lcnt[e], 1);
  __syncthreads();
  if (t < NEXP) lbase[t] = atomicAdd(&cnt[t], lcnt[t]);
  __syncthreads();
  rank[n] = lbase[e] + lr;
  float* o = out + (size_t)n * OUTW + ODIM;
#pragma unroll
  for (int j = 0; j < NEXP; j++) o[j] = (j == e) ? 1.0f : 0.0f;
}

__global__ void scan_kernel(const int* __restrict__ cnt, int* __restrict__ off) {
  if (threadIdx.x == 0) {
    int s = 0;
    for (int e = 0; e < NEXP; e++) { off[e] = s; s += cnt[e]; }
  }
}

// 4 tokens per block, one wave per token.
__global__ __launch_bounds__(256) void gather_kernel(
    const float* __restrict__ x, const int* __restrict__ idx,
    const int* __restrict__ rank, const int* __restrict__ off,
    bf16_t* __restrict__ xg, int* __restrict__ tok_of_pos) {
  int wave = threadIdx.x >> 6, lane = threadIdx.x & 63;
  int n = blockIdx.x * 4 + wave;
  int e = idx[n];
  int pos = off[e] + rank[n];
  if (lane == 0) tok_of_pos[pos] = n;
  const float4* xr = (const float4*)(x + (size_t)n * DDIM);
  bf16x4* og = (bf16x4*)(xg + (size_t)pos * DDIM);
#pragma unroll
  for (int r = 0; r < 4; r++) {
    float4 v = xr[lane + r * 64];
    bf16x4 o;
    o[0] = (bf16_t)v.x; o[1] = (bf16_t)v.y; o[2] = (bf16_t)v.z; o[3] = (bf16_t)v.w;
    og[lane + r * 64] = o;
  }
}

// transpose+convert both weights in ONE launch.
// flat id: [0,2048) -> W1 (R=1024,C=2048), [2048,4096) -> W2 (R=2048,C=1024)
// tile 128(r) x 64(c)
__global__ __launch_bounds__(256) void wtrans_kernel(
    const float* __restrict__ W1s, bf16_t* __restrict__ W1d,
    const float* __restrict__ W2s, bf16_t* __restrict__ W2d) {
  __shared__ float t[128][65];
  int id = blockIdx.x;
  const float* src; bf16_t* dst; int R, C, tid2;
  if (id < 2048) { src = W1s; dst = W1d; R = DDIM; C = HDIM; tid2 = id; }
  else           { src = W2s; dst = W2d; R = HDIM; C = ODIM; tid2 = id - 2048; }
  int ntc = C / 64;
  int e = tid2 / (ntc * (R / 128));
  int rem = tid2 % (ntc * (R / 128));
  int c0 = (rem % ntc) * 64, r0g = (rem / ntc) * 128;
  int tid = threadIdx.x;
  const float* s = src + (size_t)e * R * C;
#pragma unroll
  for (int p = 0; p < 8; p++) {
    int r = (tid >> 4) + p * 16;
    int c4 = (tid & 15) * 4;
    float4 v = *(const float4*)&s[(size_t)(r0g + r) * C + c0 + c4];
    t[r][c4 + 0] = v.x;
    t[r][c4 + 1] = v.y;
    t[r][c4 + 2] = v.z;
    t[r][c4 + 3] = v.w;
  }
  __syncthreads();
  bf16_t* d = dst + (size_t)e * R * C;
  int w = tid >> 6, l = tid & 63;
#pragma unroll
  for (int itc = 0; itc < 2; itc++) {
#pragma unroll
    for (int it2 = 0; it2 < 2; it2++) {
      int c = (l >> 3) + 8 * w + 32 * itc;
      int r0 = (l & 7) * 8 + 64 * it2;
      bf16x8 o;
#pragma unroll
      for (int j = 0; j < 8; j++) o[j] = (bf16_t)t[r0 + j][c];
      *(bf16x8*)&d[(size_t)(c0 + c) * R + r0g + r0] = o;
    }
  }
}

// C[pos][n] = sum_k A[pos][k] * Bt[e][n][k] + bias[e][n]
// 1D grid, expert = blockIdx.x & 7 -> expert pinned to one XCD (id%8 round-robin).
// BK=64 (32KB LDS): half the barrier drains of BK=32.
// LDS row = 128B = exactly 32 banks -> rows alias; XOR swizzle is REQUIRED:
//   physical 16B-chunk p at row r holds global chunk p ^ (r&7).
// Staging lane l (instr s): row=(w*4+s)*8+(l>>3), phys chunk l&7, so global
//   chunk = (l&7)^(l>>3). Fragment (q,ks) reads phys ((ks*4+q)^(mrow&7)).
//   -> every ds_read_b128: 8 lanes per bank-quad = conflict-free.
template <int KDIM, int NCOLS, int MTG, bool TO_BF16>
__global__ __launch_bounds__(256) void gemm_kernel(
    const bf16_t* __restrict__ A, const bf16_t* __restrict__ Bt,
    const float* __restrict__ bias,
    const int* __restrict__ cnt, const int* __restrict__ off,
    const int* __restrict__ tok_of_pos,
    bf16_t* __restrict__ outb, float* __restrict__ outf) {
  constexpr int NT = NCOLS / 128;
  const int b = blockIdx.x;
  const int e = b & 7;
  int t = b >> 3;
  const int mtl = t % MTG;
  t /= MTG;
  const int nt = t % NT;
  const int g = t / NT;
  const int mt = g * MTG + mtl;

  const int count = cnt[e];
  if (mt * 128 >= count) return;
  const int base = off[e];

  __shared__ bf16_t lA[128 * 64];
  __shared__ bf16_t lB[128 * 64];

  const int tid = threadIdx.x;
  const int lane = tid & 63;
  const int wave = tid >> 6;
  const int mrow = lane & 15;
  const int q = lane >> 4;
  const int wm = (wave & 1) * 64;
  const int wn = (wave >> 1) * 64;

  // staging pointers: 4 instrs each for A and B per iter
  const bf16_t* pA[4];
  const bf16_t* pB[4];
  const int gchunk = (lane & 7) ^ (lane >> 3);
#pragma unroll
  for (int s = 0; s < 4; s++) {
    int lrow = (wave * 4 + s) * 8 + (lane >> 3);
    int gr = base + mt * 128 + lrow;
    if (gr > NTOK - 1) gr = NTOK - 1;  // clamp: garbage rows masked at store
    pA[s] = A + (size_t)gr * KDIM + gchunk * 8;
    int nrow = nt * 128 + lrow;
    pB[s] = Bt + ((size_t)e * NCOLS + nrow) * KDIM + gchunk * 8;
  }

  f32x4 acc[4][4] = {};
  // fragment base: row (wm|wn + mrow), phys chunk (ks*4+q)^(mrow&7)
  const int xr = mrow & 7;
  const bf16_t* la0 = &lA[(wm + mrow) * 64];
  const bf16_t* lb0 = &lB[(wn + mrow) * 64];
  const int o0 = (q ^ xr) * 8;
  const int o1 = ((4 + q) ^ xr) * 8;

  for (int kk = 0; kk < KDIM; kk += 64) {
#pragma unroll
    for (int s = 0; s < 4; s++) {
      gld_lds16(&lA[(wave * 4 + s) * 512], pA[s] + kk);
      gld_lds16(&lB[(wave * 4 + s) * 512], pB[s] + kk);
    }
    __syncthreads();
#pragma unroll
    for (int ks = 0; ks < 2; ks++) {
      const int o = ks ? o1 : o0;
      bf16x8 af[4], bfr[4];
#pragma unroll
      for (int i = 0; i < 4; i++) {
        af[i]  = *(const bf16x8*)(la0 + i * 16 * 64 + o);
        bfr[i] = *(const bf16x8*)(lb0 + i * 16 * 64 + o);
      }
#pragma unroll
      for (int i = 0; i < 4; i++)
#pragma unroll
        for (int j = 0; j < 4; j++)
          acc[i][j] = __builtin_amdgcn_mfma_f32_16x16x32_bf16(af[i], bfr[j], acc[i][j], 0, 0, 0);
    }
    __syncthreads();
  }

  const int mlimit = count - mt * 128;
  float bs[4];
#pragma unroll
  for (int j = 0; j < 4; j++)
    bs[j] = bias[(size_t)e * NCOLS + nt * 128 + wn + j * 16 + mrow];

#pragma unroll
  for (int i = 0; i < 4; i++) {
#pragma unroll
    for (int r = 0; r < 4; r++) {
      int ml = wm + i * 16 + q * 4 + r;
      if (ml < mlimit) {
        int prow = base + mt * 128 + ml;
        if constexpr (TO_BF16) {
          bf16_t* orow = outb + (size_t)prow * NCOLS;
#pragma unroll
          for (int j = 0; j < 4; j++)
            orow[nt * 128 + wn + j * 16 + mrow] = (bf16_t)(acc[i][j][r] + bs[j]);
        } else {
          int tok = tok_of_pos[prow];
          float* orow = outf + (size_t)tok * OUTW;
#pragma unroll
          for (int j = 0; j < 4; j++)
            orow[nt * 128 + wn + j * 16 + mrow] = acc[i][j][r] + bs[j];
        }
      }
    }
  }
}

extern "C" void kernel_launch(void* const* d_in, const int* in_sizes, int n_in,
                              void* d_out, int out_size, void* d_ws, size_t ws_size,
                              hipStream_t stream) {
  const float* x  = (const float*)d_in[0];
  const float* W1 = (const float*)d_in[1];
  const float* b1 = (const float*)d_in[2];
  const float* W2 = (const float*)d_in[3];
  const float* b2 = (const float*)d_in[4];
  const int* idx  = (const int*)d_in[5];
  float* out = (float*)d_out;

  char* ws = (char*)d_ws;
  bf16_t* xg  = (bf16_t*)(ws);                 // 16 MB  [N][D] bf16
  bf16_t* hg  = (bf16_t*)(ws + 16777216);      // 32 MB  [N][H] bf16
  bf16_t* Wt1 = (bf16_t*)(ws + 50331648);      // 32 MB  [E][H][D] bf16
  bf16_t* Wt2 = (bf16_t*)(ws + 83886080);      // 32 MB  [E][O][H] bf16
  int* tok    = (int*)(ws + 117440512);        // 32 KB
  int* rank   = (int*)(ws + 117473280);        // 32 KB
  int* cnt    = (int*)(ws + 117506048);
  int* off    = (int*)(ws + 117506080);

  zero_cnt_kernel<<<1, 64, 0, stream>>>(cnt);
  route_kernel<<<NTOK / 256, 256, 0, stream>>>(idx, out, rank, cnt);
  scan_kernel<<<1, 64, 0, stream>>>(cnt, off);
  gather_kernel<<<NTOK / 4, 256, 0, stream>>>(x, idx, rank, off, xg, tok);
  wtrans_kernel<<<4096, 256, 0, stream>>>(W1, Wt1, W2, Wt2);
  // GEMM1: K=1024, NCOLS=2048, MTG=8 (2MB A-group)
  gemm_kernel<DDIM, HDIM, 8, true>
      <<<NEXP * MT_MAX * (HDIM / 128), 256, 0, stream>>>(
      xg, Wt1, b1, cnt, off, tok, hg, nullptr);
  // GEMM2: K=2048, NCOLS=1024, MTG=4 (2MB A-group)
  gemm_kernel<HDIM, ODIM, 4, false>
      <<<NEXP * MT_MAX * (ODIM / 128), 256, 0, stream>>>(
      hg, Wt2, b2, cnt, off, tok, nullptr, out);
}